// Round 11
// baseline (197.011 us; speedup 1.0000x reference)
//
#include <hip/hip_runtime.h>

// DenseLayerWithComplexNeurons: out = per-cell-type-MLP( x @ W^T + b )
// M = B*S = 8192, K = DIN = 1024, N = A*DOUT = 4096, DOUT = 1024
// T = 4 cell types, G = 256 neurons/type, A = 4, H = 8.
//
// R3: 256x128 BK=64 2-barrier loop. 101.6 us.
// R4-7,11: counted-vmcnt/raw-barrier pipelines: all >= 112 us. CLOSED.
// R8: forced 3 blocks on 220-reg waves: acc spills. 113.5 us.
// R9: BK=32 dbuf, stage(t+1)->compute(t)->syncthreads. 97.4 us.
// R10: lane-local epilogue via W-row perm (zero-LDS epilogue). 96.6 us.
// R12: 2-wave blocks (same regs/wave): 126 us. R13: 32x128 waves, 64-reg
//   acc, 3 w/SIMD: occupancy 37% but 101.9 us -- TLP doesn't pay; kernel
//   runs near SUM of pipes (MFMA 65K + LDS 98K + VALU ~90K cyc vs wall
//   232K). Reducible term = LDS pipe.
// R14: B never touches LDS. cvt packs wb in exact MFMA fragment order
//   [nb][kt][kh][a][lane]x16B -> per-fragment one coalesced 1KB
//   global_load_dwordx4 stream from L2 (B-panel ~1MB/CU total). LDS/
//   barriers are A-only (BK=64 dbuf, 2x32KB, R3-verified staging+frag
//   addrs; R9-verified loop order). LDS reads/CU 74K->25K cyc, barriers
//   32->16, B loads software-pipelined by compiler (no barrier dep).
//   Geometry/epilogue = R10 verbatim (64x128 waves, acc[2][4], 2 blk/CU).

typedef __bf16 bf16x8 __attribute__((ext_vector_type(8)));
typedef float f32x4 __attribute__((ext_vector_type(4)));
typedef float f32x16 __attribute__((ext_vector_type(16)));

#define BM 256
#define BN 128
#define BK 64
#define KDIM 1024
#define NT 16                        // K / BK
#define ABUF 32768                   // A bytes per buffer (256 rows x 64 k x 2B)
#define XN8 (8192 * 1024 / 8)
#define WN8 (4096 * 1024 / 8)

__global__ __launch_bounds__(256) void cvt_bf16_kernel(
    const float* __restrict__ x, const float* __restrict__ w,
    __bf16* __restrict__ xb, __bf16* __restrict__ wb) {
    int i = blockIdx.x * 256 + threadIdx.x;
    const float* src;
    __bf16* dst;
    int j, jdst;
    if (i < XN8) { src = x; dst = xb; j = i; jdst = i; }
    else {
        src = w; dst = wb; j = i - XN8;
        // Pack W into MFMA-fragment order. 8-elem unit j covers orig row
        // r = j>>7, cols (j&127)*8..+8. Neuron q = r>>2, arity a = r&3,
        // n-block nb = q>>5, lane-row l5 = q&31; k: kt = c8>>3 (64-k tile),
        // kh = (c8>>1)&3 (16-k step), lk = c8&1 (8-k half, lane>=32).
        // Dest unit = ((((nb*16 + kt)*4 + kh)*4 + a)<<6) + lk*32 + l5.
        // Bijective: q = nb*32+l5, r = 4q+a, c8 = kt*8+kh*2+lk.  [checked]
        const int r  = j >> 7;
        const int c8 = j & 127;
        const int q  = r >> 2;
        const int a  = r & 3;
        const int nb = q >> 5;
        const int l5 = q & 31;
        const int kt = c8 >> 3;
        const int kh = (c8 >> 1) & 3;
        const int lk = c8 & 1;
        jdst = ((((nb * 16 + kt) * 4 + kh) * 4 + a) << 6) + lk * 32 + l5;
    }
    const f32x4* p = (const f32x4*)src + 2 * (size_t)j;
    f32x4 a = p[0], b = p[1];
    bf16x8 o;
    o[0] = (__bf16)a[0]; o[1] = (__bf16)a[1]; o[2] = (__bf16)a[2]; o[3] = (__bf16)a[3];
    o[4] = (__bf16)b[0]; o[5] = (__bf16)b[1]; o[6] = (__bf16)b[2]; o[7] = (__bf16)b[3];
    ((bf16x8*)dst)[jdst] = o;
}

__global__ __launch_bounds__(256, 2) void fused_gemm_mlp_kernel(
    const __bf16* __restrict__ Ag,   // [8192][1024] bf16 (x)
    const __bf16* __restrict__ Bg,   // fragment-packed weight (see cvt)
    const float* __restrict__ bias,  // [4096] (original order)
    const float* __restrict__ cw1,   // [4][4][8]
    const float* __restrict__ cb1,   // [4][8]
    const float* __restrict__ cw2,   // [4][8]
    const float* __restrict__ cb2,   // [4]
    float* __restrict__ out)         // [8192][1024]
{
    __shared__ __align__(16) unsigned char raw[2 * ABUF];   // 65536 B (A only)

    const int tid  = threadIdx.x;
    const int wave = tid >> 6;       // 0..3 = m quarter (64 rows each)
    const int lane = tid & 63;
    const int nb  = blockIdx.x;      // n-block (128 cols)
    const int bm0 = blockIdx.y * BM; // m offset in [0,8192)
    const int bn0 = nb * BN;

    f32x16 acc[2][4] = {};           // 2 m-tiles x 4 a-subtiles of 32x32

    // ---- A staging lane map (R3-verified, BK=64, 8-row/1KB chunks) ----
    const int srow  = lane >> 3;
    const int scol8 = (((lane & 7) ^ srow) * 8);

    // ---- A fragment LDS byte addresses (R3-verified formula) ----
    // MFMA 32x32x16: row = lane&31, k = kh*16 + (lane>>5)*8 + i.
    // A row = wave*64 + mi*32 + lr5; byte = row*128 + ((kh*2+lk2)^lx)*16.
    const int lr5 = lane & 31;
    const int lk2 = lane >> 5;   // 0..1
    const int lx  = lane & 7;
    int a_addr[4];
#pragma unroll
    for (int kh = 0; kh < 4; ++kh)
        a_addr[kh] = (wave * 64 + lr5) * 128 + (((kh * 2 + lk2) ^ lx) * 16);
    const char* sb = (const char*)raw;

    // ---- B fragment stream base (packed layout; 1KB coalesced per frag) ----
    // frag(t, kh, a) at Bg + nb*131072 + t*8192 + kh*2048 + a*512 + lane*8
    const __bf16* bB = Bg + (size_t)nb * 131072 + lane * 8;

    // ---- stage one A tile t into buffer (t&1): 32 chunks, 8 per wave ----
    auto stage = [&](int t) {
        const int bb = (t & 1) * ABUF;
        const int k0 = t * BK;
#pragma unroll
        for (int c = 0; c < 8; ++c) {
            const int chunk = wave + c * 4;
            const __bf16* ga = Ag + (size_t)(bm0 + chunk * 8 + srow) * KDIM + k0 + scol8;
            __builtin_amdgcn_global_load_lds(
                (__attribute__((address_space(1))) void*)ga,
                (__attribute__((address_space(3))) void*)&raw[bb + chunk * 1024],
                16, 0, 0);
        }
    };

    // ---- prologue: tile 0 staged and drained ----
    stage(0);
    __syncthreads();

    // ---- main loop: stage(t+1) -> compute(t) -> barrier (R9-verified) ----
    // B loads are plain globals (no barrier dependence; compiler pipelines).
    for (int t = 0; t < NT; ++t) {
        if (t + 1 < NT) stage(t + 1);

        const int cb = (t & 1) * ABUF;
        const __bf16* bT = bB + t * 8192;
#pragma unroll
        for (int kh = 0; kh < 4; ++kh) {
            bf16x8 af[2], bfr[4];
#pragma unroll
            for (int mi = 0; mi < 2; ++mi)
                af[mi] = *(const bf16x8*)(sb + cb + a_addr[kh] + mi * 4096);
#pragma unroll
            for (int a = 0; a < 4; ++a)
                bfr[a] = *(const bf16x8*)(bT + kh * 2048 + a * 512);
#pragma unroll
            for (int mi = 0; mi < 2; ++mi)
#pragma unroll
                for (int a = 0; a < 4; ++a)
                    acc[mi][a] = __builtin_amdgcn_mfma_f32_32x32x16_bf16(
                        af[mi], bfr[a], acc[mi][a], 0, 0, 0);
        }
        if (t + 1 < NT) __syncthreads();
    }

    // ---- epilogue: fully lane-local per-neuron MLP (R10-verified) ----
    // Lane (lr5) owns neuron q = nb*32 + lr5; acc[mi][a][g] = z(row, 4q+a)
    // with row = wave*64 + mi*32 + (g&3) + 8*(g>>2) + 4*lk2.
    const int tct = bn0 >> 10;  // cell type, block-uniform
    float w1[32], b1[8], w2[8];
#pragma unroll
    for (int i = 0; i < 32; ++i) w1[i] = cw1[tct * 32 + i];
#pragma unroll
    for (int i = 0; i < 8; ++i) { b1[i] = cb1[tct * 8 + i]; w2[i] = cw2[tct * 8 + i]; }
    const float b2 = cb2[tct];

    const f32x4 bz = *(const f32x4*)&bias[bn0 + 4 * lr5];   // components a=0..3

    const float L2E2 = 2.885390081777927f;  // 2*log2(e)
    float* outp = out + (size_t)(bm0 + wave * 64 + 4 * lk2) * 1024 + nb * 32 + lr5;

#pragma unroll
    for (int mi = 0; mi < 2; ++mi) {
#pragma unroll
        for (int g = 0; g < 16; ++g) {
            const float z0 = acc[mi][0][g] + bz[0];
            const float z1 = acc[mi][1][g] + bz[1];
            const float z2 = acc[mi][2][g] + bz[2];
            const float z3 = acc[mi][3][g] + bz[3];
            float o = 0.f;
#pragma unroll
            for (int hh = 0; hh < 8; ++hh) {
                float pre = z0 * w1[0 * 8 + hh] + z1 * w1[1 * 8 + hh]
                          + z2 * w1[2 * 8 + hh] + z3 * w1[3 * 8 + hh] + b1[hh];
                float e = __builtin_amdgcn_exp2f(pre * L2E2);        // e^(2*pre)
                float th = 1.0f - 2.0f * __builtin_amdgcn_rcpf(e + 1.0f);
                o += th * w2[hh];
            }
            o += b2;
            const int row = mi * 32 + (g & 3) + 8 * (g >> 2);  // + wave*64 + 4*lk2 in outp
            outp[(size_t)row * 1024] = o;
        }
    }
}

extern "C" void kernel_launch(void* const* d_in, const int* in_sizes, int n_in,
                              void* d_out, int out_size, void* d_ws, size_t ws_size,
                              hipStream_t stream) {
    const float* x    = (const float*)d_in[0];
    const float* w    = (const float*)d_in[1];
    const float* bias = (const float*)d_in[2];
    const float* cw1  = (const float*)d_in[3];
    const float* cb1  = (const float*)d_in[4];
    const float* cw2  = (const float*)d_in[5];
    const float* cb2  = (const float*)d_in[6];
    float* out = (float*)d_out;

    __bf16* xb = (__bf16*)d_ws;                       // 8192*1024 bf16 = 16 MB
    __bf16* wb = xb + (size_t)8192 * 1024;            // 4096*1024 bf16 = 8 MB

    cvt_bf16_kernel<<<(XN8 + WN8) / 256, 256, 0, stream>>>(x, w, xb, wb);

    dim3 grid(4096 / BN, 8192 / BM);  // (32, 32)
    fused_gemm_mlp_kernel<<<grid, 256, 0, stream>>>(xb, wb, bias, cw1, cb1, cw2, cb2, out);
}

// Round 12
// 190.310 us; speedup vs baseline: 1.0352x; 1.0352x over previous
//
#include <hip/hip_runtime.h>

// DenseLayerWithComplexNeurons: out = per-cell-type-MLP( x @ W^T + b )
// M = B*S = 8192, K = DIN = 1024, N = A*DOUT = 4096, DOUT = 1024
// T = 4 cell types, G = 256 neurons/type, A = 4, H = 8.
//
// FINAL = Round 10 configuration (session optimum, 96.6 us fused).
// Session ledger (what is closed, with evidence):
//  R3  256x128 BK=64 2-barrier: 101.6 us.
//  R4-7,11 counted-vmcnt/raw-barrier/3-buf pipelines: 134/118/FAIL/113/117
//    -- ALL lose to plain __syncthreads (compiler schedules better; guide
//    m131-m141 confirmed on this kernel).
//  R8  3 blocks/CU forced: acc spills (220 regs/wave is structural).
//  R9  BK=32 dbuf, stage(t+1)->compute(t)->sync: 97.4 (drain hidden under
//    compute -- the one structural win).
//  R10 W-row-perm lane-local epilogue (zero-LDS, zero-barrier): 96.6.
//  R12 2-wave blocks: 126 (occupancy is register-capped, not group-capped).
//  R13 64-reg acc, 37% occupancy: 101.9 (latency not occupancy-hideable).
//  R14 B-from-global frag-packed: conflicts 6.29M->2.1M as predicted,
//    103.5 us -- LDS pipe was never the limiter.
//  Floor: 711 TF effective (28.5% of dense bf16 MFMA peak; MFMA pipe 29us
//  of 96.6us wall). Remaining gap = __syncthreads drain structure; proven
//  alternatives (8-phase/hand-asm schedules) not reproducible here.

typedef __bf16 bf16x8 __attribute__((ext_vector_type(8)));
typedef float f32x4 __attribute__((ext_vector_type(4)));
typedef float f32x16 __attribute__((ext_vector_type(16)));

#define BM 256
#define BN 128
#define BK 32
#define KDIM 1024
#define NT 32                        // K / BK
#define ABUF 16384                   // A bytes per buffer (256 rows x 32 k x 2B)
#define BUFB 24576                   // per-buffer bytes: A 16K + B 8K
#define XN8 (8192 * 1024 / 8)
#define WN8 (4096 * 1024 / 8)

__global__ __launch_bounds__(256) void cvt_bf16_kernel(
    const float* __restrict__ x, const float* __restrict__ w,
    __bf16* __restrict__ xb, __bf16* __restrict__ wb) {
    int i = blockIdx.x * 256 + threadIdx.x;
    const float* src;
    __bf16* dst;
    int j, jdst;
    if (i < XN8) { src = x; dst = xb; j = i; jdst = i; }
    else {
        src = w; dst = wb; j = i - XN8;
        // W row permutation: row r = 4q+a  ->  128*(q>>5) + 32*a + (q&31)
        const int r  = j >> 7;          // 1024 cols = 128 chunks of 8
        const int c8 = j & 127;
        const int q  = r >> 2;
        const int a  = r & 3;
        const int rn = ((q >> 5) << 7) + (a << 5) + (q & 31);
        jdst = (rn << 7) + c8;
    }
    const f32x4* p = (const f32x4*)src + 2 * (size_t)j;
    f32x4 a = p[0], b = p[1];
    bf16x8 o;
    o[0] = (__bf16)a[0]; o[1] = (__bf16)a[1]; o[2] = (__bf16)a[2]; o[3] = (__bf16)a[3];
    o[4] = (__bf16)b[0]; o[5] = (__bf16)b[1]; o[6] = (__bf16)b[2]; o[7] = (__bf16)b[3];
    ((bf16x8*)dst)[jdst] = o;
}

__global__ __launch_bounds__(256, 2) void fused_gemm_mlp_kernel(
    const __bf16* __restrict__ Ag,   // [8192][1024] bf16 (x)
    const __bf16* __restrict__ Bg,   // [4096][1024] bf16 (perm'd weight, B^T layout)
    const float* __restrict__ bias,  // [4096] (original order)
    const float* __restrict__ cw1,   // [4][4][8]
    const float* __restrict__ cb1,   // [4][8]
    const float* __restrict__ cw2,   // [4][8]
    const float* __restrict__ cb2,   // [4]
    float* __restrict__ out)         // [8192][1024]
{
    __shared__ __align__(16) unsigned char raw[2 * BUFB];   // 49152 B

    const int tid  = threadIdx.x;
    const int wave = tid >> 6;       // 0..3 = m quarter (64 rows each)
    const int lane = tid & 63;
    const int wm = wave;
    const int bn0 = blockIdx.x * BN; // n offset in [0,4096)
    const int bm0 = blockIdx.y * BM; // m offset in [0,8192)

    f32x16 acc[2][4] = {};           // 2 m-tiles x 4 a-subtiles of 32x32

    // ---- staging lane mapping (row-pair physical rows; verified R9/R10) ----
    // 1KB DMA chunk = 16 rows (8 row-pairs x 128B). Lane i writes byte 16*i:
    // q_loc=i>>3, slot=i&7; source: s_log=slot^q_loc, row=2q_loc+(s_log>>2),
    // col16=s_log&3. Global (R,c) lands at chunk*1024 + ((R>>1)&7)*128 +
    // (((R&1)*4+c)^((R>>1)&7))*16 == fragment address below.
    const int qloc = lane >> 3;
    const int slog = (lane & 7) ^ qloc;
    const int arow = 2 * qloc + (slog >> 2);
    const int acol = (slog & 3) * 8;

    // ---- fragment LDS byte addresses (buffer-relative; verified R10) ----
    // MFMA 32x32x16: row = lane&31, k = kh*16 + (lane>>5)*8 + i.
    // A row = wm*64 + mi*32 + lr5 -> wm*4096 + mi*2048 + lrh*128 + slot
    // B row = a*32 + lr5          -> ABUF + a*2048 + lrh*128 + slot
    const int lr5 = lane & 31;
    const int lk2 = lane >> 5;   // 0..1
    const int lrh = lr5 >> 1;    // 0..15
    const int lp  = lr5 & 1;
    int a_addr[2], b_addr[2];
#pragma unroll
    for (int kh = 0; kh < 2; ++kh) {
        const int slot = (((lp * 4) + (kh * 2 + lk2)) ^ (lrh & 7)) * 16;
        a_addr[kh] = wm * 4096 + lrh * 128 + slot;
        b_addr[kh] = ABUF + lrh * 128 + slot;
    }
    const char* sb = (const char*)raw;

    // ---- stage one BK=32 tile t into buffer (t&1): 24 chunks, 6 per wave ----
    auto stage = [&](int t) {
        const int bb = (t & 1) * BUFB;
        const int k0 = t * BK;
#pragma unroll
        for (int c = 0; c < 4; ++c) {          // A: 16 chunks of 16 rows
            const int ch = wave + c * 4;
            const __bf16* g = Ag + (size_t)(bm0 + ch * 16 + arow) * KDIM + k0 + acol;
            __builtin_amdgcn_global_load_lds(
                (__attribute__((address_space(1))) void*)g,
                (__attribute__((address_space(3))) void*)&raw[bb + ch * 1024],
                16, 0, 0);
        }
#pragma unroll
        for (int c = 0; c < 2; ++c) {          // B: 8 chunks of 16 rows
            const int ch = wave + c * 4;
            const __bf16* g = Bg + (size_t)(bn0 + ch * 16 + arow) * KDIM + k0 + acol;
            __builtin_amdgcn_global_load_lds(
                (__attribute__((address_space(1))) void*)g,
                (__attribute__((address_space(3))) void*)&raw[bb + ABUF + ch * 1024],
                16, 0, 0);
        }
    };

    // ---- prologue: tile 0 staged and drained ----
    stage(0);
    __syncthreads();

    // ---- main loop: stage(t+1) -> compute(t) -> barrier (verified R9/R10) ----
    // Safety under plain __syncthreads semantics:
    //  - stage(t+1) writes nbuf; last reads of nbuf (compute t-1) were
    //    lgkm-drained at the barrier ending iter t-1.  (WAR ok)
    //  - compute(t) reads cbuf; every wave's stage(t) DMA drained by the
    //    implicit vmcnt(0) of the barrier ending iter t-1.  (RAW ok)
    //  - this iter's barrier drains stage(t+1) AFTER compute(t) -> DMA
    //    latency hidden under 12 ds_read_b128 + 16 MFMA.
    for (int t = 0; t < NT; ++t) {
        if (t + 1 < NT) stage(t + 1);

        const int cb = (t & 1) * BUFB;
#pragma unroll
        for (int kh = 0; kh < 2; ++kh) {
            bf16x8 af[2], bfr[4];
#pragma unroll
            for (int mi = 0; mi < 2; ++mi)
                af[mi] = *(const bf16x8*)(sb + cb + a_addr[kh] + mi * 2048);
#pragma unroll
            for (int a = 0; a < 4; ++a)
                bfr[a] = *(const bf16x8*)(sb + cb + b_addr[kh] + a * 2048);
#pragma unroll
            for (int mi = 0; mi < 2; ++mi)
#pragma unroll
                for (int a = 0; a < 4; ++a)
                    acc[mi][a] = __builtin_amdgcn_mfma_f32_32x32x16_bf16(
                        af[mi], bfr[a], acc[mi][a], 0, 0, 0);
        }
        __syncthreads();
    }

    // ---- epilogue: fully lane-local per-neuron MLP (verified R10) ----
    // Lane (lr5) owns neuron q = bn0/4 + lr5; acc[mi][a][g] = z(row, 4q+a)
    // with row = wm*64 + mi*32 + (g&3) + 8*(g>>2) + 4*lk2.
    const int tct = bn0 >> 10;  // cell type, block-uniform
    float w1[32], b1[8], w2[8];
#pragma unroll
    for (int i = 0; i < 32; ++i) w1[i] = cw1[tct * 32 + i];
#pragma unroll
    for (int i = 0; i < 8; ++i) { b1[i] = cb1[tct * 8 + i]; w2[i] = cw2[tct * 8 + i]; }
    const float b2 = cb2[tct];

    const f32x4 bz = *(const f32x4*)&bias[bn0 + 4 * lr5];   // components a=0..3

    const float L2E2 = 2.885390081777927f;  // 2*log2(e)
    float* outp = out + (size_t)(bm0 + wm * 64 + 4 * lk2) * 1024 + (bn0 >> 2) + lr5;

#pragma unroll
    for (int mi = 0; mi < 2; ++mi) {
#pragma unroll
        for (int g = 0; g < 16; ++g) {
            const float z0 = acc[mi][0][g] + bz[0];
            const float z1 = acc[mi][1][g] + bz[1];
            const float z2 = acc[mi][2][g] + bz[2];
            const float z3 = acc[mi][3][g] + bz[3];
            float o = 0.f;
#pragma unroll
            for (int hh = 0; hh < 8; ++hh) {
                float pre = z0 * w1[0 * 8 + hh] + z1 * w1[1 * 8 + hh]
                          + z2 * w1[2 * 8 + hh] + z3 * w1[3 * 8 + hh] + b1[hh];
                float e = __builtin_amdgcn_exp2f(pre * L2E2);        // e^(2*pre)
                float th = 1.0f - 2.0f * __builtin_amdgcn_rcpf(e + 1.0f);
                o += th * w2[hh];
            }
            o += b2;
            const int row = mi * 32 + (g & 3) + 8 * (g >> 2);  // + wm*64 + 4*lk2 in outp
            outp[(size_t)row * 1024] = o;
        }
    }
}

extern "C" void kernel_launch(void* const* d_in, const int* in_sizes, int n_in,
                              void* d_out, int out_size, void* d_ws, size_t ws_size,
                              hipStream_t stream) {
    const float* x    = (const float*)d_in[0];
    const float* w    = (const float*)d_in[1];
    const float* bias = (const float*)d_in[2];
    const float* cw1  = (const float*)d_in[3];
    const float* cb1  = (const float*)d_in[4];
    const float* cw2  = (const float*)d_in[5];
    const float* cb2  = (const float*)d_in[6];
    float* out = (float*)d_out;

    __bf16* xb = (__bf16*)d_ws;                       // 8192*1024 bf16 = 16 MB
    __bf16* wb = xb + (size_t)8192 * 1024;            // 4096*1024 bf16 = 8 MB

    cvt_bf16_kernel<<<(XN8 + WN8) / 256, 256, 0, stream>>>(x, w, xb, wb);

    dim3 grid(4096 / BN, 8192 / BM);  // (32, 32)
    fused_gemm_mlp_kernel<<<grid, 256, 0, stream>>>(xb, wb, bias, cw1, cb1, cw2, cb2, out);
}